// Round 20
// baseline (342.163 us; speedup 1.0000x reference)
//
#include <hip/hip_runtime.h>

typedef __attribute__((ext_vector_type(8))) short bf16x8;
typedef __attribute__((ext_vector_type(2))) unsigned uint2v;
typedef __attribute__((ext_vector_type(4))) float f32x4;

#define MFMA_BF16(a, b, c) __builtin_amdgcn_mfma_f32_16x16x32_bf16((a), (b), (c), 0, 0, 0)
#define VMCNT(N) asm volatile("s_waitcnt vmcnt(" #N ")" ::: "memory")
#define BAR() asm volatile("s_barrier" ::: "memory")

__device__ __forceinline__ unsigned short bf16rn(float f) {
  unsigned u = __builtin_bit_cast(unsigned, f);
  u += 0x7fffu + ((u >> 16) & 1u);
  return (unsigned short)(u >> 16);
}

__device__ __forceinline__ void gld_lds16(const void* g, void* l) {
  __builtin_amdgcn_global_load_lds((const __attribute__((address_space(1))) void*)g,
                                   (__attribute__((address_space(3))) void*)l, 16, 0, 0);
}

// ---------------- weight convert + transpose: W[K][N] f32 -> W^T[N][K] bf16 ----------------
// LDS-bounce transpose: coalesced float4 row reads -> T[64][65] (pad kills transposed-read
// conflicts: banks 4k mod 32, 2-way = free) -> coalesced ushort4 writes along K.
__global__ __launch_bounds__(256) void convT_kernel(
    const float* __restrict__ wq, const float* __restrict__ wk,
    const float* __restrict__ wv, const float* __restrict__ wo,
    const float* __restrict__ wfc, const float* __restrict__ wpj,
    unsigned short* __restrict__ wsb)
{
  const int bid = blockIdx.x;
  const float* src; unsigned short* dst; int K, N, lb;
  if (bid < 1024) {
    const int m = bid >> 8; lb = bid & 255; K = 1024; N = 1024;
    src = (m == 0) ? wq : (m == 1) ? wk : (m == 2) ? wv : wo;
    dst = wsb + (size_t)m * 1048576u;
  } else if (bid < 2048) {
    lb = bid - 1024; K = 1024; N = 4096; src = wfc; dst = wsb + 4194304u;
  } else {
    lb = bid - 2048; K = 4096; N = 1024; src = wpj; dst = wsb + 8388608u;
  }
  const int tiles_k = K >> 6;
  const int tk = lb % tiles_k, tn = lb / tiles_k;
  const int k0 = tk << 6, n0 = tn << 6;

  __shared__ float T[64][65];
  const int t = threadIdx.x;
  const int rr = t >> 4, cc = t & 15;
#pragma unroll
  for (int i = 0; i < 4; ++i) {
    const float4 v = *(const float4*)(src + (size_t)(k0 + i * 16 + rr) * N + n0 + cc * 4);
    T[i * 16 + rr][cc * 4 + 0] = v.x;
    T[i * 16 + rr][cc * 4 + 1] = v.y;
    T[i * 16 + rr][cc * 4 + 2] = v.z;
    T[i * 16 + rr][cc * 4 + 3] = v.w;
  }
  __syncthreads();
#pragma unroll
  for (int j = 0; j < 4; ++j) {
    const int nr = j * 16 + rr;
    ushort4 o;
    o.x = bf16rn(T[cc * 4 + 0][nr]);
    o.y = bf16rn(T[cc * 4 + 1][nr]);
    o.z = bf16rn(T[cc * 4 + 2][nr]);
    o.w = bf16rn(T[cc * 4 + 3][nr]);
    *(ushort4*)(dst + (size_t)(n0 + nr) * K + k0 + cc * 4) = o;
  }
}

// ---------------- layernorm: f32 [rows][1024] -> bf16 ----------------
__global__ __launch_bounds__(256) void ln_kernel(
    const float* __restrict__ x, const float* __restrict__ sc,
    const float* __restrict__ sh, unsigned short* __restrict__ out)
{
  const int row = blockIdx.x, t = threadIdx.x;
  const float4 v = *(const float4*)(x + (size_t)row * 1024 + t * 4);
  float s = v.x + v.y + v.z + v.w;
  float q = v.x * v.x + v.y * v.y + v.z * v.z + v.w * v.w;
#pragma unroll
  for (int off = 1; off < 64; off <<= 1) { s += __shfl_xor(s, off); q += __shfl_xor(q, off); }
  __shared__ float ps[4], pq[4];
  if ((t & 63) == 0) { ps[t >> 6] = s; pq[t >> 6] = q; }
  __syncthreads();
  s = ps[0] + ps[1] + ps[2] + ps[3];
  q = pq[0] + pq[1] + pq[2] + pq[3];
  const float mean = s * (1.f / 1024.f);
  const float var = q * (1.f / 1024.f) - mean * mean;
  const float inv = rsqrtf(var + 1e-5f);
  const float4 scv = *(const float4*)(sc + t * 4);
  const float4 shv = *(const float4*)(sh + t * 4);
  ushort4 o;
  o.x = bf16rn((v.x - mean) * inv * scv.x + shv.x);
  o.y = bf16rn((v.y - mean) * inv * scv.y + shv.y);
  o.z = bf16rn((v.z - mean) * inv * scv.z + shv.z);
  o.w = bf16rn((v.w - mean) * inv * scv.w + shv.w);
  *(ushort4*)(out + (size_t)row * 1024 + t * 4) = o;
}

// ---------------- 128x128 BK=64 GEMM: 3 blocks/CU (48KB LDS), counted vmcnt --------------
template<int EPI>
__global__ __launch_bounds__(256, 3) void g128(
    const unsigned short* __restrict__ A, const unsigned short* __restrict__ Bt,
    int N, int K,
    unsigned short* __restrict__ outb, float* __restrict__ outf,
    const float* __restrict__ bias, const float* __restrict__ resid)
{
  extern __shared__ char smem[];
  const int t = threadIdx.x, lane = t & 63, w = t >> 6;
  const int g = lane >> 4, l15 = lane & 15;
  const int wr = w >> 1, wc = w & 1;  // 2M x 2N waves; wave tile 64 x 64
  const int bid = blockIdx.x;
  const int tm = (bid & 7) * 8 + ((bid >> 3) & 7);
  const int tn = bid >> 6;
  const int m0 = tm << 7, n0 = tn << 7;

  const int srow = t >> 3;
  const int colswz = (((t & 7) ^ (srow & 7)) << 3);
  const unsigned short* pA = A + (size_t)(m0 + srow) * K + colswz;
  const unsigned short* pB = Bt + (size_t)(n0 + srow) * K + colswz;
  const int ldw = w << 10;

  auto stA = [&](int TT) {
#pragma unroll
    for (int i = 0; i < 4; ++i)
      gld_lds16(pA + TT * 64 + (size_t)(i * 32) * K, smem + i * 4096 + ldw);
  };
  auto stB02 = [&](int TT, char* buf) {
    gld_lds16(pB + TT * 64, buf + ldw);
    gld_lds16(pB + TT * 64 + (size_t)64 * K, buf + 8192 + ldw);
  };
  auto stB13 = [&](int TT, char* buf) {
    gld_lds16(pB + TT * 64 + (size_t)32 * K, buf + 4096 + ldw);
    gld_lds16(pB + TT * 64 + (size_t)96 * K, buf + 12288 + ldw);
  };

  const int sw0 = (((0 + g) ^ (l15 & 7)) << 4);
  const int sw1 = (((4 + g) ^ (l15 & 7)) << 4);
  const int NT = K >> 6;

  f32x4 acc[4][4] = {};
  bf16x8 av[4][2], bv0[2][2], bv1[2][2];

#define LDA_ALL() { _Pragma("unroll") for (int mi = 0; mi < 4; ++mi) {                    \
    const int row_ = (wr * 64 + mi * 16 + l15) * 128;                                     \
    av[mi][0] = *(const bf16x8*)(smem + row_ + sw0);                                      \
    av[mi][1] = *(const bf16x8*)(smem + row_ + sw1); } }
#define LDB_H(CB, H, BV) { _Pragma("unroll") for (int ni = 0; ni < 2; ++ni) {             \
    const int row_ = (wc * 64 + (H) * 32 + ni * 16 + l15) * 128;                          \
    BV[ni][0] = *(const bf16x8*)((CB) + row_ + sw0);                                      \
    BV[ni][1] = *(const bf16x8*)((CB) + row_ + sw1); } }
#define MMH(BV, H) { __builtin_amdgcn_s_setprio(1);                                       \
    _Pragma("unroll") for (int mi = 0; mi < 4; ++mi)                                      \
      _Pragma("unroll") for (int ni = 0; ni < 2; ++ni) {                                  \
        acc[mi][(H)*2+ni] = MFMA_BF16(av[mi][0], BV[ni][0], acc[mi][(H)*2+ni]);           \
        acc[mi][(H)*2+ni] = MFMA_BF16(av[mi][1], BV[ni][1], acc[mi][(H)*2+ni]);  }        \
    __builtin_amdgcn_s_setprio(0); }

  // prologue: A(0) + B02(0) + B13(0) -> buffers; B02(1) -> B[1]; prove tile 0
  stA(0); stB02(0, smem + 16384); stB13(0, smem + 16384);
  stB02(1, smem + 32768);
  VMCNT(2);
  BAR();

  for (int kt = 0; kt < NT; ++kt) {
    char* bc = smem + 16384 + (kt & 1) * 16384;
    char* bn = smem + 16384 + ((kt & 1) ^ 1) * 16384;
    // ---- p0: A(all) + B chunks{0,2} ----
    LDA_ALL();
    LDB_H(bc, 0, bv0);
    if (kt + 1 < NT) stB13(kt + 1, bn);
    BAR();
    MMH(bv0, 0);
    BAR();
    // ---- p1: B chunks{1,3}; refill A and B02 dead regions ----
    LDB_H(bc, 1, bv1);
    if (kt + 1 < NT) stA(kt + 1);
    if (kt + 2 < NT) stB02(kt + 2, bc);
    BAR();
    MMH(bv1, 1);
    if (kt + 2 < NT) VMCNT(2);
    else if (kt + 1 < NT) VMCNT(0);
    BAR();
  }
#undef LDA_ALL
#undef LDB_H
#undef MMH

  if constexpr (EPI == 2) {
#pragma unroll
    for (int mi = 0; mi < 4; ++mi) {
      const int ro = mi * 16 + g * 4;
#pragma unroll
      for (int ci = 0; ci < 4; ++ci) {
        const int n = n0 + wc * 64 + ((ci >> 1) << 5) + ((ci & 1) << 4) + l15;
        const float bn = bias[n];
#pragma unroll
        for (int r = 0; r < 4; ++r) {
          const size_t m = m0 + wr * 64 + ro + r;
          outf[m * N + n] = acc[mi][ci][r] + bn + resid[m * N + n];
        }
      }
    }
  } else if constexpr (EPI == 1) {  // transposed store for V
    __syncthreads();
    unsigned short* T = (unsigned short*)(smem + w * 9216);  // [64 n][72 m-padded]
#pragma unroll
    for (int mi = 0; mi < 4; ++mi)
#pragma unroll
      for (int ci = 0; ci < 4; ++ci) {
        const int co = ((ci >> 1) << 5) + ((ci & 1) << 4);
#pragma unroll
        for (int r = 0; r < 4; ++r)
          T[(co + l15) * 72 + mi * 16 + 4 * g + r] = bf16rn(acc[mi][ci][r]);
      }
    asm volatile("s_waitcnt lgkmcnt(0)" ::: "memory");
    const int bidx = m0 >> 11;
    const int srw = (m0 & 2047) + wr * 64 + ((lane & 7) << 3);
#pragma unroll
    for (int rr = 0; rr < 8; ++rr) {
      const int trow = rr * 8 + (lane >> 3);
      bf16x8 v = *(const bf16x8*)((char*)T + trow * 144 + ((lane & 7) << 4));
      *(bf16x8*)(outb + (size_t)(bidx * 1024 + n0 + wc * 64 + trow) * 2048 + srw) = v;
    }
  } else {  // EPI 0 / 3: bf16 store via rotated bounce (conflict-free writes)
    __syncthreads();
    char* wsl = smem + w * 8192;  // per-wave bounce [64 rows][128B, rows byte-rotated]
#pragma unroll
    for (int mi = 0; mi < 4; ++mi) {
      const int ro = mi * 16 + g * 4;
#pragma unroll
      for (int ci = 0; ci < 4; ++ci) {
        const int co = ((ci >> 1) << 5) + ((ci & 1) << 4) + l15;
        float bn = 0.f;
        if constexpr (EPI == 3) bn = bias[n0 + wc * 64 + co];
#pragma unroll
        for (int r = 0; r < 4; ++r) {
          float v = acc[mi][ci][r];
          if constexpr (EPI == 3) {
            v += bn;
            // gelu(u) = u / (1 + exp2(-2.3022085*(u+0.044715u^3)))
            const float inner = v + 0.044715f * v * v * v;
            const float s = exp2f(-2.3022085f * inner);
            v = v / (1.0f + s);
          }
          *(unsigned short*)(wsl + (ro + r) * 128 + ((co * 2 + g * 32) & 127)) = bf16rn(v);
        }
      }
    }
    // same-wave LDS RAW ordered by compiler lgkmcnt; rotation cancels: chunk c -> cols c*8..+7
#pragma unroll
    for (int s = 0; s < 8; ++s) {
      const int row = s * 8 + (lane >> 3);
      bf16x8 vv = *(const bf16x8*)(wsl + row * 128 +
                                   (((lane & 7) * 16 + ((row >> 2) & 3) * 32) & 127));
      *(bf16x8*)(outb + (size_t)(m0 + wr * 64 + row) * N + n0 + wc * 64 + (lane & 7) * 8) = vv;
    }
  }
}

// ---------------- flash attention, causal, D=64, QB=128 (8 waves x 16 rows), KB=64 --------
__global__ __launch_bounds__(512) void attn_kernel(
    const unsigned short* __restrict__ qg, const unsigned short* __restrict__ kg,
    const unsigned short* __restrict__ vT, unsigned short* __restrict__ ctx)
{
  __shared__ char smem[36864];  // K 8KB | V 8KB | Pt 8 x 2560
  const int bh = blockIdx.x, b = bh >> 4, h = bh & 15;
  const int t = threadIdx.x, lane = t & 63, w = t >> 6, g = lane >> 4, l15 = lane & 15;
  char* Ks = smem;
  char* Vs = smem + 8192;
  char* Pt = smem + 16384 + w * 2560;  // per-wave [64 kv][40B]

  const float SC = 0.18033688011112042f;  // 0.125 * log2(e)

  const int srow = t >> 3;
  const int ssw = ((((t & 7) << 4) ^ ((srow & 7) << 4)) >> 1);

  for (int pass = 0; pass < 2; ++pass) {
    const int qt = pass ? 15 - (int)blockIdx.y : (int)blockIdx.y;
    const int q0 = qt << 7;
    const int q0w = q0 + w * 16;

    bf16x8 qf[2];
#pragma unroll
    for (int ks = 0; ks < 2; ++ks)
      qf[ks] = *(const bf16x8*)(qg + (size_t)(b * 2048 + q0w + l15) * 2048 +
                                h * 64 + ks * 32 + g * 8);

    f32x4 acc[4] = {};
    float lsum[4] = {};

    const int ntile = 2 * qt + 2;
    for (int kt = 0; kt < ntile; ++kt) {
      const int kv0 = kt << 6;
      __syncthreads();
      gld_lds16(kg + (size_t)(b * 2048 + kv0 + srow) * 2048 + h * 64 + ssw,
                Ks + ((t >> 3) << 7));
      gld_lds16(vT + (size_t)(b * 1024 + h * 64 + srow) * 2048 + kv0 + ssw,
                Vs + ((t >> 3) << 7));
      __syncthreads();

      f32x4 sf[4] = {};
#pragma unroll
      for (int nb = 0; nb < 4; ++nb) {
        const int krow = nb * 16 + l15;
#pragma unroll
        for (int ks = 0; ks < 2; ++ks) {
          bf16x8 kf = *(const bf16x8*)(Ks + krow * 128 +
                                       (((ks * 32 + g * 8) << 1) ^ ((krow & 7) << 4)));
          sf[nb] = MFMA_BF16(qf[ks], kf, sf[nb]);
        }
      }
      if (kv0 + 63 > q0w) {  // causal mask (wave-uniform branch)
#pragma unroll
        for (int nb = 0; nb < 4; ++nb)
#pragma unroll
          for (int r = 0; r < 4; ++r) {
            const int qq = q0w + 4 * g + r;
            const int kk = kv0 + nb * 16 + l15;
            if (kk > qq) sf[nb][r] = -__builtin_inff();
          }
      }
#pragma unroll
      for (int nb = 0; nb < 4; ++nb)
#pragma unroll
        for (int r = 0; r < 4; ++r) {
          const float p = exp2f(__builtin_fmaf(sf[nb][r], SC, -4.0f));
          sf[nb][r] = p;
          lsum[r] += p;
        }
#pragma unroll
      for (int nb = 0; nb < 4; ++nb) {
        uint2v dw;
        asm("v_cvt_pk_bf16_f32 %0, %1, %2"
            : "=v"(dw.x) : "v"(sf[nb][0]), "v"(sf[nb][1]));
        asm("v_cvt_pk_bf16_f32 %0, %1, %2"
            : "=v"(dw.y) : "v"(sf[nb][2]), "v"(sf[nb][3]));
        *(uint2v*)(Pt + (nb * 16 + l15) * 40 + (g << 3)) = dw;
      }
      asm volatile("s_waitcnt lgkmcnt(0)" ::: "memory");  // same-wave P RAW
#pragma unroll
      for (int ks = 0; ks < 2; ++ks) {
        const char* pp = Pt + (ks * 32 + g * 8) * 40 + (l15 << 1);
        bf16x8 pa;
#pragma unroll
        for (int jj = 0; jj < 8; ++jj)
          pa[jj] = *(const short*)(pp + jj * 40);
#pragma unroll
        for (int nb = 0; nb < 4; ++nb) {
          const int drow = nb * 16 + l15;
          bf16x8 vb = *(const bf16x8*)(Vs + drow * 128 +
                                       (((ks * 32 + g * 8) << 1) ^ ((drow & 7) << 4)));
          acc[nb] = MFMA_BF16(pa, vb, acc[nb]);
        }
      }
    }
#pragma unroll
    for (int r = 0; r < 4; ++r) {
      float s = lsum[r];
      s += __shfl_xor(s, 1);
      s += __shfl_xor(s, 2);
      s += __shfl_xor(s, 4);
      s += __shfl_xor(s, 8);
      lsum[r] = s;
    }
    float inv[4];
#pragma unroll
    for (int r = 0; r < 4; ++r) inv[r] = 1.0f / lsum[r];
#pragma unroll
    for (int nb = 0; nb < 4; ++nb)
#pragma unroll
      for (int r = 0; r < 4; ++r)
        ctx[(size_t)(b * 2048 + q0w + 4 * g + r) * 1024 + h * 64 + nb * 16 + l15] =
            bf16rn(acc[nb][r] * inv[r]);
  }
}

extern "C" void kernel_launch(void* const* d_in, const int* in_sizes, int n_in,
                              void* d_out, int out_size, void* d_ws, size_t ws_size,
                              hipStream_t stream)
{
  const float* x   = (const float*)d_in[0];
  const float* l1s = (const float*)d_in[1];
  const float* l1b = (const float*)d_in[2];
  const float* l2s = (const float*)d_in[3];
  const float* l2b = (const float*)d_in[4];
  const float* Wq  = (const float*)d_in[5];
  const float* Wk  = (const float*)d_in[6];
  const float* Wv  = (const float*)d_in[7];
  const float* Wo  = (const float*)d_in[8];
  const float* bo  = (const float*)d_in[9];
  const float* Wfc = (const float*)d_in[10];
  const float* bfc = (const float*)d_in[11];
  const float* Wpj = (const float*)d_in[12];
  const float* bpj = (const float*)d_in[13];
  float* out = (float*)d_out;
  char* ws = (char*)d_ws;

  unsigned short* wT   = (unsigned short*)ws;                // 24MB weights
  unsigned short* wqkT = wT;                                 // [2048][1024] fused Q|K
  unsigned short* wvT  = wT + 2097152u;
  unsigned short* woT  = wT + 3145728u;
  unsigned short* wfcT = wT + 4194304u;
  unsigned short* wpjT = wT + 8388608u;
  unsigned short* ln1x = (unsigned short*)(ws + 25165824u);  // 16MB
  unsigned short* qkb  = (unsigned short*)(ws + 41943040u);  // 32MB [8192][2048]
  unsigned short* vTb  = (unsigned short*)(ws + 75497472u);  // 16MB
  unsigned short* ctx  = (unsigned short*)(ws + 92274688u);  // 16MB (reused as ln2x)
  unsigned short* ln2x = ctx;
  float* hbuf          = (float*)(ws + 109051904u);          // 32MB
  unsigned short* fcb  = (unsigned short*)(ws + 25165824u);  // 64MB, reuses ln1x..vTb

  convT_kernel<<<3072, 256, 0, stream>>>(Wq, Wk, Wv, Wo, Wfc, Wpj, wT);
  ln_kernel<<<8192, 256, 0, stream>>>(x, l1s, l1b, ln1x);
  g128<0><<<1024, 256, 49152, stream>>>(ln1x, wqkT, 2048, 1024,
                                        qkb, nullptr, nullptr, nullptr);
  g128<1><<<512, 256, 49152, stream>>>(ln1x, wvT, 1024, 1024,
                                       vTb, nullptr, nullptr, nullptr);
  attn_kernel<<<dim3(64, 8), 512, 0, stream>>>(qkb, qkb + 1024, vTb, ctx);
  g128<2><<<512, 256, 49152, stream>>>(ctx, woT, 1024, 1024,
                                       nullptr, hbuf, bo, x);
  ln_kernel<<<8192, 256, 0, stream>>>(hbuf, l2s, l2b, ln2x);
  g128<3><<<2048, 256, 49152, stream>>>(ln2x, wfcT, 4096, 1024,
                                        fcb, nullptr, bfc, nullptr);
  g128<2><<<512, 256, 49152, stream>>>(fcb, wpjT, 1024, 4096,
                                       nullptr, out, bpj, hbuf);
}

// Round 21
// 336.208 us; speedup vs baseline: 1.0177x; 1.0177x over previous
//
#include <hip/hip_runtime.h>

typedef __attribute__((ext_vector_type(8))) short bf16x8;
typedef __attribute__((ext_vector_type(2))) unsigned uint2v;
typedef __attribute__((ext_vector_type(4))) float f32x4;

#define MFMA_BF16(a, b, c) __builtin_amdgcn_mfma_f32_16x16x32_bf16((a), (b), (c), 0, 0, 0)
#define VMCNT(N) asm volatile("s_waitcnt vmcnt(" #N ")" ::: "memory")
#define BAR() asm volatile("s_barrier" ::: "memory")

__device__ __forceinline__ unsigned short bf16rn(float f) {
  unsigned u = __builtin_bit_cast(unsigned, f);
  u += 0x7fffu + ((u >> 16) & 1u);
  return (unsigned short)(u >> 16);
}

__device__ __forceinline__ void gld_lds16(const void* g, void* l) {
  __builtin_amdgcn_global_load_lds((const __attribute__((address_space(1))) void*)g,
                                   (__attribute__((address_space(3))) void*)l, 16, 0, 0);
}

// ---------------- weight convert + transpose: W[K][N] f32 -> W^T[N][K] bf16 ----------------
// LDS-bounce transpose: coalesced float4 row reads -> T[64][65] (pad kills transposed-read
// conflicts) -> coalesced ushort4 writes along K.
__global__ __launch_bounds__(256) void convT_kernel(
    const float* __restrict__ wq, const float* __restrict__ wk,
    const float* __restrict__ wv, const float* __restrict__ wo,
    const float* __restrict__ wfc, const float* __restrict__ wpj,
    unsigned short* __restrict__ wsb)
{
  const int bid = blockIdx.x;
  const float* src; unsigned short* dst; int K, N, lb;
  if (bid < 1024) {
    const int m = bid >> 8; lb = bid & 255; K = 1024; N = 1024;
    src = (m == 0) ? wq : (m == 1) ? wk : (m == 2) ? wv : wo;
    dst = wsb + (size_t)m * 1048576u;
  } else if (bid < 2048) {
    lb = bid - 1024; K = 1024; N = 4096; src = wfc; dst = wsb + 4194304u;
  } else {
    lb = bid - 2048; K = 4096; N = 1024; src = wpj; dst = wsb + 8388608u;
  }
  const int tiles_k = K >> 6;
  const int tk = lb % tiles_k, tn = lb / tiles_k;
  const int k0 = tk << 6, n0 = tn << 6;

  __shared__ float T[64][65];
  const int t = threadIdx.x;
  const int rr = t >> 4, cc = t & 15;
#pragma unroll
  for (int i = 0; i < 4; ++i) {
    const float4 v = *(const float4*)(src + (size_t)(k0 + i * 16 + rr) * N + n0 + cc * 4);
    T[i * 16 + rr][cc * 4 + 0] = v.x;
    T[i * 16 + rr][cc * 4 + 1] = v.y;
    T[i * 16 + rr][cc * 4 + 2] = v.z;
    T[i * 16 + rr][cc * 4 + 3] = v.w;
  }
  __syncthreads();
#pragma unroll
  for (int j = 0; j < 4; ++j) {
    const int nr = j * 16 + rr;
    ushort4 o;
    o.x = bf16rn(T[cc * 4 + 0][nr]);
    o.y = bf16rn(T[cc * 4 + 1][nr]);
    o.z = bf16rn(T[cc * 4 + 2][nr]);
    o.w = bf16rn(T[cc * 4 + 3][nr]);
    *(ushort4*)(dst + (size_t)(n0 + nr) * K + k0 + cc * 4) = o;
  }
}

// ---------------- layernorm: f32 [rows][1024] -> bf16 ----------------
__global__ __launch_bounds__(256) void ln_kernel(
    const float* __restrict__ x, const float* __restrict__ sc,
    const float* __restrict__ sh, unsigned short* __restrict__ out)
{
  const int row = blockIdx.x, t = threadIdx.x;
  const float4 v = *(const float4*)(x + (size_t)row * 1024 + t * 4);
  float s = v.x + v.y + v.z + v.w;
  float q = v.x * v.x + v.y * v.y + v.z * v.z + v.w * v.w;
#pragma unroll
  for (int off = 1; off < 64; off <<= 1) { s += __shfl_xor(s, off); q += __shfl_xor(q, off); }
  __shared__ float ps[4], pq[4];
  if ((t & 63) == 0) { ps[t >> 6] = s; pq[t >> 6] = q; }
  __syncthreads();
  s = ps[0] + ps[1] + ps[2] + ps[3];
  q = pq[0] + pq[1] + pq[2] + pq[3];
  const float mean = s * (1.f / 1024.f);
  const float var = q * (1.f / 1024.f) - mean * mean;
  const float inv = rsqrtf(var + 1e-5f);
  const float4 scv = *(const float4*)(sc + t * 4);
  const float4 shv = *(const float4*)(sh + t * 4);
  ushort4 o;
  o.x = bf16rn((v.x - mean) * inv * scv.x + shv.x);
  o.y = bf16rn((v.y - mean) * inv * scv.y + shv.y);
  o.z = bf16rn((v.z - mean) * inv * scv.z + shv.z);
  o.w = bf16rn((v.w - mean) * inv * scv.w + shv.w);
  *(ushort4*)(out + (size_t)row * 1024 + t * 4) = o;
}

// ---------------- 128x128 BK=64 GEMM: 3 blocks/CU (48KB LDS), counted vmcnt --------------
template<int EPI>
__global__ __launch_bounds__(256, 3) void g128(
    const unsigned short* __restrict__ A, const unsigned short* __restrict__ Bt,
    int N, int K,
    unsigned short* __restrict__ outb, float* __restrict__ outf,
    const float* __restrict__ bias, const float* __restrict__ resid)
{
  extern __shared__ char smem[];
  const int t = threadIdx.x, lane = t & 63, w = t >> 6;
  const int g = lane >> 4, l15 = lane & 15;
  const int wr = w >> 1, wc = w & 1;  // 2M x 2N waves; wave tile 64 x 64
  const int bid = blockIdx.x;
  const int tm = (bid & 7) * 8 + ((bid >> 3) & 7);
  const int tn = bid >> 6;
  const int m0 = tm << 7, n0 = tn << 7;

  const int srow = t >> 3;
  const int colswz = (((t & 7) ^ (srow & 7)) << 3);
  const unsigned short* pA = A + (size_t)(m0 + srow) * K + colswz;
  const unsigned short* pB = Bt + (size_t)(n0 + srow) * K + colswz;
  const int ldw = w << 10;

  auto stA = [&](int TT) {
#pragma unroll
    for (int i = 0; i < 4; ++i)
      gld_lds16(pA + TT * 64 + (size_t)(i * 32) * K, smem + i * 4096 + ldw);
  };
  auto stB02 = [&](int TT, char* buf) {
    gld_lds16(pB + TT * 64, buf + ldw);
    gld_lds16(pB + TT * 64 + (size_t)64 * K, buf + 8192 + ldw);
  };
  auto stB13 = [&](int TT, char* buf) {
    gld_lds16(pB + TT * 64 + (size_t)32 * K, buf + 4096 + ldw);
    gld_lds16(pB + TT * 64 + (size_t)96 * K, buf + 12288 + ldw);
  };

  const int sw0 = (((0 + g) ^ (l15 & 7)) << 4);
  const int sw1 = (((4 + g) ^ (l15 & 7)) << 4);
  const int NT = K >> 6;

  f32x4 acc[4][4] = {};
  bf16x8 av[4][2], bv0[2][2], bv1[2][2];

#define LDA_ALL() { _Pragma("unroll") for (int mi = 0; mi < 4; ++mi) {                    \
    const int row_ = (wr * 64 + mi * 16 + l15) * 128;                                     \
    av[mi][0] = *(const bf16x8*)(smem + row_ + sw0);                                      \
    av[mi][1] = *(const bf16x8*)(smem + row_ + sw1); } }
#define LDB_H(CB, H, BV) { _Pragma("unroll") for (int ni = 0; ni < 2; ++ni) {             \
    const int row_ = (wc * 64 + (H) * 32 + ni * 16 + l15) * 128;                          \
    BV[ni][0] = *(const bf16x8*)((CB) + row_ + sw0);                                      \
    BV[ni][1] = *(const bf16x8*)((CB) + row_ + sw1); } }
#define MMH(BV, H) { __builtin_amdgcn_s_setprio(1);                                       \
    _Pragma("unroll") for (int mi = 0; mi < 4; ++mi)                                      \
      _Pragma("unroll") for (int ni = 0; ni < 2; ++ni) {                                  \
        acc[mi][(H)*2+ni] = MFMA_BF16(av[mi][0], BV[ni][0], acc[mi][(H)*2+ni]);           \
        acc[mi][(H)*2+ni] = MFMA_BF16(av[mi][1], BV[ni][1], acc[mi][(H)*2+ni]);  }        \
    __builtin_amdgcn_s_setprio(0); }

  // prologue: A(0) + B02(0) + B13(0) -> buffers; B02(1) -> B[1]; prove tile 0
  stA(0); stB02(0, smem + 16384); stB13(0, smem + 16384);
  stB02(1, smem + 32768);
  VMCNT(2);
  BAR();

  for (int kt = 0; kt < NT; ++kt) {
    char* bc = smem + 16384 + (kt & 1) * 16384;
    char* bn = smem + 16384 + ((kt & 1) ^ 1) * 16384;
    // ---- p0: A(all) + B chunks{0,2} ----
    LDA_ALL();
    LDB_H(bc, 0, bv0);
    if (kt + 1 < NT) stB13(kt + 1, bn);
    BAR();
    MMH(bv0, 0);
    BAR();
    // ---- p1: B chunks{1,3}; refill A and B02 dead regions ----
    LDB_H(bc, 1, bv1);
    if (kt + 1 < NT) stA(kt + 1);
    if (kt + 2 < NT) stB02(kt + 2, bc);
    BAR();
    MMH(bv1, 1);
    if (kt + 2 < NT) VMCNT(2);
    else if (kt + 1 < NT) VMCNT(0);
    BAR();
  }
#undef LDA_ALL
#undef LDB_H
#undef MMH

  if constexpr (EPI == 2) {
#pragma unroll
    for (int mi = 0; mi < 4; ++mi) {
      const int ro = mi * 16 + g * 4;
#pragma unroll
      for (int ci = 0; ci < 4; ++ci) {
        const int n = n0 + wc * 64 + ((ci >> 1) << 5) + ((ci & 1) << 4) + l15;
        const float bn = bias[n];
#pragma unroll
        for (int r = 0; r < 4; ++r) {
          const size_t m = m0 + wr * 64 + ro + r;
          outf[m * N + n] = acc[mi][ci][r] + bn + resid[m * N + n];
        }
      }
    }
  } else if constexpr (EPI == 1) {  // transposed store for V
    __syncthreads();
    unsigned short* T = (unsigned short*)(smem + w * 9216);  // [64 n][72 m-padded]
#pragma unroll
    for (int mi = 0; mi < 4; ++mi)
#pragma unroll
      for (int ci = 0; ci < 4; ++ci) {
        const int co = ((ci >> 1) << 5) + ((ci & 1) << 4);
#pragma unroll
        for (int r = 0; r < 4; ++r)
          T[(co + l15) * 72 + mi * 16 + 4 * g + r] = bf16rn(acc[mi][ci][r]);
      }
    asm volatile("s_waitcnt lgkmcnt(0)" ::: "memory");
    const int bidx = m0 >> 11;
    const int srw = (m0 & 2047) + wr * 64 + ((lane & 7) << 3);
#pragma unroll
    for (int rr = 0; rr < 8; ++rr) {
      const int trow = rr * 8 + (lane >> 3);
      bf16x8 v = *(const bf16x8*)((char*)T + trow * 144 + ((lane & 7) << 4));
      *(bf16x8*)(outb + (size_t)(bidx * 1024 + n0 + wc * 64 + trow) * 2048 + srw) = v;
    }
  } else {  // EPI 0 / 3: bf16 store via rotated bounce (conflict-free writes)
    __syncthreads();
    char* wsl = smem + w * 8192;  // per-wave bounce [64 rows][128B, rows byte-rotated]
#pragma unroll
    for (int mi = 0; mi < 4; ++mi) {
      const int ro = mi * 16 + g * 4;
#pragma unroll
      for (int ci = 0; ci < 4; ++ci) {
        const int co = ((ci >> 1) << 5) + ((ci & 1) << 4) + l15;
        float bn = 0.f;
        if constexpr (EPI == 3) bn = bias[n0 + wc * 64 + co];
#pragma unroll
        for (int r = 0; r < 4; ++r) {
          float v = acc[mi][ci][r];
          if constexpr (EPI == 3) {
            v += bn;
            // gelu(u) = u / (1 + exp2(-2.3022085*(u+0.044715u^3)))
            const float inner = v + 0.044715f * v * v * v;
            const float s = exp2f(-2.3022085f * inner);
            v = v / (1.0f + s);
          }
          *(unsigned short*)(wsl + (ro + r) * 128 + ((co * 2 + g * 32) & 127)) = bf16rn(v);
        }
      }
    }
    // same-wave LDS RAW ordered by compiler lgkmcnt; rotation cancels: chunk c -> cols c*8..+7
#pragma unroll
    for (int s = 0; s < 8; ++s) {
      const int row = s * 8 + (lane >> 3);
      bf16x8 vv = *(const bf16x8*)(wsl + row * 128 +
                                   (((lane & 7) * 16 + ((row >> 2) & 3) * 32) & 127));
      *(bf16x8*)(outb + (size_t)(m0 + wr * 64 + row) * N + n0 + wc * 64 + (lane & 7) * 8) = vv;
    }
  }
}

// ---------------- flash attention, causal, D=64, QB=128 (8 waves x 16 rows), KB=64 --------
// K/V double-buffered (g128 ledger, simplest form): issue stage(t+1)->bn at body top
// (bn's readers finished before end-of-(t-1) barrier; ntile block-uniform so barrier
// counts align), compute t from bc, VMCNT(0) [drains only the 2 body-top ops, issued a
// full compute earlier] + one barrier per tile. Pass boundary: ntile even -> last reads
// from buf1 while next pass's prologue writes buf0.
__global__ __launch_bounds__(512) void attn_kernel(
    const unsigned short* __restrict__ qg, const unsigned short* __restrict__ kg,
    const unsigned short* __restrict__ vT, unsigned short* __restrict__ ctx)
{
  __shared__ char smem[53248];  // KV dbuf 2 x (K 8KB | V 8KB) | Pt 8 x 2560
  const int bh = blockIdx.x, b = bh >> 4, h = bh & 15;
  const int t = threadIdx.x, lane = t & 63, w = t >> 6, g = lane >> 4, l15 = lane & 15;
  char* Pt = smem + 32768 + w * 2560;  // per-wave [64 kv][40B]

  const float SC = 0.18033688011112042f;  // 0.125 * log2(e)

  const int srow = t >> 3;
  const int ssw = ((((t & 7) << 4) ^ ((srow & 7) << 4)) >> 1);
  const int ldst = srow << 7;

  auto stage = [&](int kt, char* buf) {
    const int kv0 = kt << 6;
    gld_lds16(kg + (size_t)(b * 2048 + kv0 + srow) * 2048 + h * 64 + ssw, buf + ldst);
    gld_lds16(vT + (size_t)(b * 1024 + h * 64 + srow) * 2048 + kv0 + ssw,
              buf + 8192 + ldst);
  };

  for (int pass = 0; pass < 2; ++pass) {
    const int qt = pass ? 15 - (int)blockIdx.y : (int)blockIdx.y;
    const int q0 = qt << 7;
    const int q0w = q0 + w * 16;

    bf16x8 qf[2];
#pragma unroll
    for (int ks = 0; ks < 2; ++ks)
      qf[ks] = *(const bf16x8*)(qg + (size_t)(b * 2048 + q0w + l15) * 2048 +
                                h * 64 + ks * 32 + g * 8);

    f32x4 acc[4] = {};
    float lsum[4] = {};

    const int ntile = 2 * qt + 2;
    stage(0, smem);
    VMCNT(0);
    BAR();
    for (int kt = 0; kt < ntile; ++kt) {
      const int kv0 = kt << 6;
      char* bc = smem + (kt & 1) * 16384;
      char* bn = smem + ((kt & 1) ^ 1) * 16384;
      if (kt + 1 < ntile) stage(kt + 1, bn);
      char* Ks = bc;
      char* Vs = bc + 8192;

      f32x4 sf[4] = {};
#pragma unroll
      for (int nb = 0; nb < 4; ++nb) {
        const int krow = nb * 16 + l15;
#pragma unroll
        for (int ks = 0; ks < 2; ++ks) {
          bf16x8 kf = *(const bf16x8*)(Ks + krow * 128 +
                                       (((ks * 32 + g * 8) << 1) ^ ((krow & 7) << 4)));
          sf[nb] = MFMA_BF16(qf[ks], kf, sf[nb]);
        }
      }
      if (kv0 + 63 > q0w) {  // causal mask (wave-uniform branch)
#pragma unroll
        for (int nb = 0; nb < 4; ++nb)
#pragma unroll
          for (int r = 0; r < 4; ++r) {
            const int qq = q0w + 4 * g + r;
            const int kk = kv0 + nb * 16 + l15;
            if (kk > qq) sf[nb][r] = -__builtin_inff();
          }
      }
#pragma unroll
      for (int nb = 0; nb < 4; ++nb)
#pragma unroll
        for (int r = 0; r < 4; ++r) {
          const float p = exp2f(__builtin_fmaf(sf[nb][r], SC, -4.0f));
          sf[nb][r] = p;
          lsum[r] += p;
        }
#pragma unroll
      for (int nb = 0; nb < 4; ++nb) {
        uint2v dw;
        asm("v_cvt_pk_bf16_f32 %0, %1, %2"
            : "=v"(dw.x) : "v"(sf[nb][0]), "v"(sf[nb][1]));
        asm("v_cvt_pk_bf16_f32 %0, %1, %2"
            : "=v"(dw.y) : "v"(sf[nb][2]), "v"(sf[nb][3]));
        *(uint2v*)(Pt + (nb * 16 + l15) * 40 + (g << 3)) = dw;
      }
      asm volatile("s_waitcnt lgkmcnt(0)" ::: "memory");  // same-wave P RAW
#pragma unroll
      for (int ks = 0; ks < 2; ++ks) {
        const char* pp = Pt + (ks * 32 + g * 8) * 40 + (l15 << 1);
        bf16x8 pa;
#pragma unroll
        for (int jj = 0; jj < 8; ++jj)
          pa[jj] = *(const short*)(pp + jj * 40);
#pragma unroll
        for (int nb = 0; nb < 4; ++nb) {
          const int drow = nb * 16 + l15;
          bf16x8 vb = *(const bf16x8*)(Vs + drow * 128 +
                                       (((ks * 32 + g * 8) << 1) ^ ((drow & 7) << 4)));
          acc[nb] = MFMA_BF16(pa, vb, acc[nb]);
        }
      }
      VMCNT(0);  // drains only the 2 body-top stage ops (issued one compute-body ago)
      BAR();
    }
    // one 16-lane sum reduce per q-row
#pragma unroll
    for (int r = 0; r < 4; ++r) {
      float s = lsum[r];
      s += __shfl_xor(s, 1);
      s += __shfl_xor(s, 2);
      s += __shfl_xor(s, 4);
      s += __shfl_xor(s, 8);
      lsum[r] = s;
    }
    float inv[4];
#pragma unroll
    for (int r = 0; r < 4; ++r) inv[r] = 1.0f / lsum[r];
#pragma unroll
    for (int nb = 0; nb < 4; ++nb)
#pragma unroll
      for (int r = 0; r < 4; ++r)
        ctx[(size_t)(b * 2048 + q0w + 4 * g + r) * 1024 + h * 64 + nb * 16 + l15] =
            bf16rn(acc[nb][r] * inv[r]);
  }
}

extern "C" void kernel_launch(void* const* d_in, const int* in_sizes, int n_in,
                              void* d_out, int out_size, void* d_ws, size_t ws_size,
                              hipStream_t stream)
{
  const float* x   = (const float*)d_in[0];
  const float* l1s = (const float*)d_in[1];
  const float* l1b = (const float*)d_in[2];
  const float* l2s = (const float*)d_in[3];
  const float* l2b = (const float*)d_in[4];
  const float* Wq  = (const float*)d_in[5];
  const float* Wk  = (const float*)d_in[6];
  const float* Wv  = (const float*)d_in[7];
  const float* Wo  = (const float*)d_in[8];
  const float* bo  = (const float*)d_in[9];
  const float* Wfc = (const float*)d_in[10];
  const float* bfc = (const float*)d_in[11];
  const float* Wpj = (const float*)d_in[12];
  const float* bpj = (const float*)d_in[13];
  float* out = (float*)d_out;
  char* ws = (char*)d_ws;

  unsigned short* wT   = (unsigned short*)ws;                // 24MB weights
  unsigned short* wqkT = wT;                                 // [2048][1024] fused Q|K
  unsigned short* wvT  = wT + 2097152u;
  unsigned short* woT  = wT + 3145728u;
  unsigned short* wfcT = wT + 4194304u;
  unsigned short* wpjT = wT + 8388608u;
  unsigned short* ln1x = (unsigned short*)(ws + 25165824u);  // 16MB
  unsigned short* qkb  = (unsigned short*)(ws + 41943040u);  // 32MB [8192][2048]
  unsigned short* vTb  = (unsigned short*)(ws + 75497472u);  // 16MB
  unsigned short* ctx  = (unsigned short*)(ws + 92274688u);  // 16MB (reused as ln2x)
  unsigned short* ln2x = ctx;
  float* hbuf          = (float*)(ws + 109051904u);          // 32MB
  unsigned short* fcb  = (unsigned short*)(ws + 25165824u);  // 64MB, reuses ln1x..vTb

  convT_kernel<<<3072, 256, 0, stream>>>(Wq, Wk, Wv, Wo, Wfc, Wpj, wT);
  ln_kernel<<<8192, 256, 0, stream>>>(x, l1s, l1b, ln1x);
  g128<0><<<1024, 256, 49152, stream>>>(ln1x, wqkT, 2048, 1024,
                                        qkb, nullptr, nullptr, nullptr);
  g128<1><<<512, 256, 49152, stream>>>(ln1x, wvT, 1024, 1024,
                                       vTb, nullptr, nullptr, nullptr);
  attn_kernel<<<dim3(64, 8), 512, 0, stream>>>(qkb, qkb + 1024, vTb, ctx);
  g128<2><<<512, 256, 49152, stream>>>(ctx, woT, 1024, 1024,
                                       nullptr, hbuf, bo, x);
  ln_kernel<<<8192, 256, 0, stream>>>(hbuf, l2s, l2b, ln2x);
  g128<3><<<2048, 256, 49152, stream>>>(ln2x, wfcT, 4096, 1024,
                                        fcb, nullptr, bfc, nullptr);
  g128<2><<<512, 256, 49152, stream>>>(fcb, wpjT, 1024, 4096,
                                       nullptr, out, bpj, hbuf);
}

// Round 22
// 335.009 us; speedup vs baseline: 1.0214x; 1.0036x over previous
//
#include <hip/hip_runtime.h>

typedef __attribute__((ext_vector_type(8))) short bf16x8;
typedef __attribute__((ext_vector_type(2))) unsigned uint2v;
typedef __attribute__((ext_vector_type(4))) float f32x4;

#define MFMA_BF16(a, b, c) __builtin_amdgcn_mfma_f32_16x16x32_bf16((a), (b), (c), 0, 0, 0)
#define VMCNT(N) asm volatile("s_waitcnt vmcnt(" #N ")" ::: "memory")
#define BAR() asm volatile("s_barrier" ::: "memory")

__device__ __forceinline__ unsigned short bf16rn(float f) {
  unsigned u = __builtin_bit_cast(unsigned, f);
  u += 0x7fffu + ((u >> 16) & 1u);
  return (unsigned short)(u >> 16);
}

__device__ __forceinline__ void gld_lds16(const void* g, void* l) {
  __builtin_amdgcn_global_load_lds((const __attribute__((address_space(1))) void*)g,
                                   (__attribute__((address_space(3))) void*)l, 16, 0, 0);
}

// ---------------- weight convert + transpose: W[K][N] f32 -> W^T[N][K] bf16 ----------------
// LDS-bounce transpose: coalesced float4 row reads -> T[64][65] (pad kills transposed-read
// conflicts) -> coalesced ushort4 writes along K.
__global__ __launch_bounds__(256) void convT_kernel(
    const float* __restrict__ wq, const float* __restrict__ wk,
    const float* __restrict__ wv, const float* __restrict__ wo,
    const float* __restrict__ wfc, const float* __restrict__ wpj,
    unsigned short* __restrict__ wsb)
{
  const int bid = blockIdx.x;
  const float* src; unsigned short* dst; int K, N, lb;
  if (bid < 1024) {
    const int m = bid >> 8; lb = bid & 255; K = 1024; N = 1024;
    src = (m == 0) ? wq : (m == 1) ? wk : (m == 2) ? wv : wo;
    dst = wsb + (size_t)m * 1048576u;
  } else if (bid < 2048) {
    lb = bid - 1024; K = 1024; N = 4096; src = wfc; dst = wsb + 4194304u;
  } else {
    lb = bid - 2048; K = 4096; N = 1024; src = wpj; dst = wsb + 8388608u;
  }
  const int tiles_k = K >> 6;
  const int tk = lb % tiles_k, tn = lb / tiles_k;
  const int k0 = tk << 6, n0 = tn << 6;

  __shared__ float T[64][65];
  const int t = threadIdx.x;
  const int rr = t >> 4, cc = t & 15;
#pragma unroll
  for (int i = 0; i < 4; ++i) {
    const float4 v = *(const float4*)(src + (size_t)(k0 + i * 16 + rr) * N + n0 + cc * 4);
    T[i * 16 + rr][cc * 4 + 0] = v.x;
    T[i * 16 + rr][cc * 4 + 1] = v.y;
    T[i * 16 + rr][cc * 4 + 2] = v.z;
    T[i * 16 + rr][cc * 4 + 3] = v.w;
  }
  __syncthreads();
#pragma unroll
  for (int j = 0; j < 4; ++j) {
    const int nr = j * 16 + rr;
    ushort4 o;
    o.x = bf16rn(T[cc * 4 + 0][nr]);
    o.y = bf16rn(T[cc * 4 + 1][nr]);
    o.z = bf16rn(T[cc * 4 + 2][nr]);
    o.w = bf16rn(T[cc * 4 + 3][nr]);
    *(ushort4*)(dst + (size_t)(n0 + nr) * K + k0 + cc * 4) = o;
  }
}

// ---------------- layernorm: f32 [rows][1024] -> bf16 ----------------
__global__ __launch_bounds__(256) void ln_kernel(
    const float* __restrict__ x, const float* __restrict__ sc,
    const float* __restrict__ sh, unsigned short* __restrict__ out)
{
  const int row = blockIdx.x, t = threadIdx.x;
  const float4 v = *(const float4*)(x + (size_t)row * 1024 + t * 4);
  float s = v.x + v.y + v.z + v.w;
  float q = v.x * v.x + v.y * v.y + v.z * v.z + v.w * v.w;
#pragma unroll
  for (int off = 1; off < 64; off <<= 1) { s += __shfl_xor(s, off); q += __shfl_xor(q, off); }
  __shared__ float ps[4], pq[4];
  if ((t & 63) == 0) { ps[t >> 6] = s; pq[t >> 6] = q; }
  __syncthreads();
  s = ps[0] + ps[1] + ps[2] + ps[3];
  q = pq[0] + pq[1] + pq[2] + pq[3];
  const float mean = s * (1.f / 1024.f);
  const float var = q * (1.f / 1024.f) - mean * mean;
  const float inv = rsqrtf(var + 1e-5f);
  const float4 scv = *(const float4*)(sc + t * 4);
  const float4 shv = *(const float4*)(sh + t * 4);
  ushort4 o;
  o.x = bf16rn((v.x - mean) * inv * scv.x + shv.x);
  o.y = bf16rn((v.y - mean) * inv * scv.y + shv.y);
  o.z = bf16rn((v.z - mean) * inv * scv.z + shv.z);
  o.w = bf16rn((v.w - mean) * inv * scv.w + shv.w);
  *(ushort4*)(out + (size_t)row * 1024 + t * 4) = o;
}

// ---------------- 128x128 BK=64 GEMM: 3 blocks/CU (48KB LDS), counted vmcnt --------------
template<int EPI>
__global__ __launch_bounds__(256, 3) void g128(
    const unsigned short* __restrict__ A, const unsigned short* __restrict__ Bt,
    int N, int K,
    unsigned short* __restrict__ outb, float* __restrict__ outf,
    const float* __restrict__ bias, const float* __restrict__ resid)
{
  extern __shared__ char smem[];
  const int t = threadIdx.x, lane = t & 63, w = t >> 6;
  const int g = lane >> 4, l15 = lane & 15;
  const int wr = w >> 1, wc = w & 1;  // 2M x 2N waves; wave tile 64 x 64
  const int bid = blockIdx.x;
  const int tm = (bid & 7) * 8 + ((bid >> 3) & 7);
  const int tn = bid >> 6;
  const int m0 = tm << 7, n0 = tn << 7;

  const int srow = t >> 3;
  const int colswz = (((t & 7) ^ (srow & 7)) << 3);
  const unsigned short* pA = A + (size_t)(m0 + srow) * K + colswz;
  const unsigned short* pB = Bt + (size_t)(n0 + srow) * K + colswz;
  const int ldw = w << 10;

  auto stA = [&](int TT) {
#pragma unroll
    for (int i = 0; i < 4; ++i)
      gld_lds16(pA + TT * 64 + (size_t)(i * 32) * K, smem + i * 4096 + ldw);
  };
  auto stB02 = [&](int TT, char* buf) {
    gld_lds16(pB + TT * 64, buf + ldw);
    gld_lds16(pB + TT * 64 + (size_t)64 * K, buf + 8192 + ldw);
  };
  auto stB13 = [&](int TT, char* buf) {
    gld_lds16(pB + TT * 64 + (size_t)32 * K, buf + 4096 + ldw);
    gld_lds16(pB + TT * 64 + (size_t)96 * K, buf + 12288 + ldw);
  };

  const int sw0 = (((0 + g) ^ (l15 & 7)) << 4);
  const int sw1 = (((4 + g) ^ (l15 & 7)) << 4);
  const int NT = K >> 6;

  f32x4 acc[4][4] = {};
  bf16x8 av[4][2], bv0[2][2], bv1[2][2];

#define LDA_ALL() { _Pragma("unroll") for (int mi = 0; mi < 4; ++mi) {                    \
    const int row_ = (wr * 64 + mi * 16 + l15) * 128;                                     \
    av[mi][0] = *(const bf16x8*)(smem + row_ + sw0);                                      \
    av[mi][1] = *(const bf16x8*)(smem + row_ + sw1); } }
#define LDB_H(CB, H, BV) { _Pragma("unroll") for (int ni = 0; ni < 2; ++ni) {             \
    const int row_ = (wc * 64 + (H) * 32 + ni * 16 + l15) * 128;                          \
    BV[ni][0] = *(const bf16x8*)((CB) + row_ + sw0);                                      \
    BV[ni][1] = *(const bf16x8*)((CB) + row_ + sw1); } }
#define MMH(BV, H) { __builtin_amdgcn_s_setprio(1);                                       \
    _Pragma("unroll") for (int mi = 0; mi < 4; ++mi)                                      \
      _Pragma("unroll") for (int ni = 0; ni < 2; ++ni) {                                  \
        acc[mi][(H)*2+ni] = MFMA_BF16(av[mi][0], BV[ni][0], acc[mi][(H)*2+ni]);           \
        acc[mi][(H)*2+ni] = MFMA_BF16(av[mi][1], BV[ni][1], acc[mi][(H)*2+ni]);  }        \
    __builtin_amdgcn_s_setprio(0); }

  // prologue: A(0) + B02(0) + B13(0) -> buffers; B02(1) -> B[1]; prove tile 0
  stA(0); stB02(0, smem + 16384); stB13(0, smem + 16384);
  stB02(1, smem + 32768);
  VMCNT(2);
  BAR();

  for (int kt = 0; kt < NT; ++kt) {
    char* bc = smem + 16384 + (kt & 1) * 16384;
    char* bn = smem + 16384 + ((kt & 1) ^ 1) * 16384;
    // ---- p0: A(all) + B chunks{0,2} ----
    LDA_ALL();
    LDB_H(bc, 0, bv0);
    if (kt + 1 < NT) stB13(kt + 1, bn);
    BAR();
    MMH(bv0, 0);
    BAR();
    // ---- p1: B chunks{1,3}; refill A and B02 dead regions ----
    LDB_H(bc, 1, bv1);
    if (kt + 1 < NT) stA(kt + 1);
    if (kt + 2 < NT) stB02(kt + 2, bc);
    BAR();
    MMH(bv1, 1);
    if (kt + 2 < NT) VMCNT(2);
    else if (kt + 1 < NT) VMCNT(0);
    BAR();
  }
#undef LDA_ALL
#undef LDB_H
#undef MMH

  if constexpr (EPI == 2) {
#pragma unroll
    for (int mi = 0; mi < 4; ++mi) {
      const int ro = mi * 16 + g * 4;
#pragma unroll
      for (int ci = 0; ci < 4; ++ci) {
        const int n = n0 + wc * 64 + ((ci >> 1) << 5) + ((ci & 1) << 4) + l15;
        const float bn = bias[n];
#pragma unroll
        for (int r = 0; r < 4; ++r) {
          const size_t m = m0 + wr * 64 + ro + r;
          outf[m * N + n] = acc[mi][ci][r] + bn + resid[m * N + n];
        }
      }
    }
  } else if constexpr (EPI == 1) {  // transposed store for V
    __syncthreads();
    unsigned short* T = (unsigned short*)(smem + w * 9216);  // [64 n][72 m-padded]
#pragma unroll
    for (int mi = 0; mi < 4; ++mi)
#pragma unroll
      for (int ci = 0; ci < 4; ++ci) {
        const int co = ((ci >> 1) << 5) + ((ci & 1) << 4);
#pragma unroll
        for (int r = 0; r < 4; ++r)
          T[(co + l15) * 72 + mi * 16 + 4 * g + r] = bf16rn(acc[mi][ci][r]);
      }
    asm volatile("s_waitcnt lgkmcnt(0)" ::: "memory");
    const int bidx = m0 >> 11;
    const int srw = (m0 & 2047) + wr * 64 + ((lane & 7) << 3);
#pragma unroll
    for (int rr = 0; rr < 8; ++rr) {
      const int trow = rr * 8 + (lane >> 3);
      bf16x8 v = *(const bf16x8*)((char*)T + trow * 144 + ((lane & 7) << 4));
      *(bf16x8*)(outb + (size_t)(bidx * 1024 + n0 + wc * 64 + trow) * 2048 + srw) = v;
    }
  } else {  // EPI 0 / 3: bf16 store via rotated bounce (conflict-free writes)
    __syncthreads();
    char* wsl = smem + w * 8192;  // per-wave bounce [64 rows][128B, rows byte-rotated]
#pragma unroll
    for (int mi = 0; mi < 4; ++mi) {
      const int ro = mi * 16 + g * 4;
#pragma unroll
      for (int ci = 0; ci < 4; ++ci) {
        const int co = ((ci >> 1) << 5) + ((ci & 1) << 4) + l15;
        float bn = 0.f;
        if constexpr (EPI == 3) bn = bias[n0 + wc * 64 + co];
#pragma unroll
        for (int r = 0; r < 4; ++r) {
          float v = acc[mi][ci][r];
          if constexpr (EPI == 3) {
            v += bn;
            // gelu(u) = u / (1 + exp2(-2.3022085*(u+0.044715u^3)))
            const float inner = v + 0.044715f * v * v * v;
            const float s = exp2f(-2.3022085f * inner);
            v = v / (1.0f + s);
          }
          *(unsigned short*)(wsl + (ro + r) * 128 + ((co * 2 + g * 32) & 127)) = bf16rn(v);
        }
      }
    }
    // same-wave LDS RAW ordered by compiler lgkmcnt; rotation cancels: chunk c -> cols c*8..+7
#pragma unroll
    for (int s = 0; s < 8; ++s) {
      const int row = s * 8 + (lane >> 3);
      bf16x8 vv = *(const bf16x8*)(wsl + row * 128 +
                                   (((lane & 7) * 16 + ((row >> 2) & 3) * 32) & 127));
      *(bf16x8*)(outb + (size_t)(m0 + wr * 64 + row) * N + n0 + wc * 64 + (lane & 7) * 8) = vv;
    }
  }
}

// ---------------- flash attention, causal, D=64, QB=128 (8 waves x 16 rows), KB=64 --------
// K/V double-buffered (counted-drain ledger); T5 setprio around QK and PV MFMA clusters.
__global__ __launch_bounds__(512) void attn_kernel(
    const unsigned short* __restrict__ qg, const unsigned short* __restrict__ kg,
    const unsigned short* __restrict__ vT, unsigned short* __restrict__ ctx)
{
  __shared__ char smem[53248];  // KV dbuf 2 x (K 8KB | V 8KB) | Pt 8 x 2560
  const int bh = blockIdx.x, b = bh >> 4, h = bh & 15;
  const int t = threadIdx.x, lane = t & 63, w = t >> 6, g = lane >> 4, l15 = lane & 15;
  char* Pt = smem + 32768 + w * 2560;  // per-wave [64 kv][40B]

  const float SC = 0.18033688011112042f;  // 0.125 * log2(e)

  const int srow = t >> 3;
  const int ssw = ((((t & 7) << 4) ^ ((srow & 7) << 4)) >> 1);
  const int ldst = srow << 7;

  auto stage = [&](int kt, char* buf) {
    const int kv0 = kt << 6;
    gld_lds16(kg + (size_t)(b * 2048 + kv0 + srow) * 2048 + h * 64 + ssw, buf + ldst);
    gld_lds16(vT + (size_t)(b * 1024 + h * 64 + srow) * 2048 + kv0 + ssw,
              buf + 8192 + ldst);
  };

  for (int pass = 0; pass < 2; ++pass) {
    const int qt = pass ? 15 - (int)blockIdx.y : (int)blockIdx.y;
    const int q0 = qt << 7;
    const int q0w = q0 + w * 16;

    bf16x8 qf[2];
#pragma unroll
    for (int ks = 0; ks < 2; ++ks)
      qf[ks] = *(const bf16x8*)(qg + (size_t)(b * 2048 + q0w + l15) * 2048 +
                                h * 64 + ks * 32 + g * 8);

    f32x4 acc[4] = {};
    float lsum[4] = {};

    const int ntile = 2 * qt + 2;
    stage(0, smem);
    VMCNT(0);
    BAR();
    for (int kt = 0; kt < ntile; ++kt) {
      const int kv0 = kt << 6;
      char* bc = smem + (kt & 1) * 16384;
      char* bn = smem + ((kt & 1) ^ 1) * 16384;
      if (kt + 1 < ntile) stage(kt + 1, bn);
      char* Ks = bc;
      char* Vs = bc + 8192;

      f32x4 sf[4] = {};
      __builtin_amdgcn_s_setprio(1);
#pragma unroll
      for (int nb = 0; nb < 4; ++nb) {
        const int krow = nb * 16 + l15;
#pragma unroll
        for (int ks = 0; ks < 2; ++ks) {
          bf16x8 kf = *(const bf16x8*)(Ks + krow * 128 +
                                       (((ks * 32 + g * 8) << 1) ^ ((krow & 7) << 4)));
          sf[nb] = MFMA_BF16(qf[ks], kf, sf[nb]);
        }
      }
      __builtin_amdgcn_s_setprio(0);
      if (kv0 + 63 > q0w) {  // causal mask (wave-uniform branch)
#pragma unroll
        for (int nb = 0; nb < 4; ++nb)
#pragma unroll
          for (int r = 0; r < 4; ++r) {
            const int qq = q0w + 4 * g + r;
            const int kk = kv0 + nb * 16 + l15;
            if (kk > qq) sf[nb][r] = -__builtin_inff();
          }
      }
#pragma unroll
      for (int nb = 0; nb < 4; ++nb)
#pragma unroll
        for (int r = 0; r < 4; ++r) {
          const float p = exp2f(__builtin_fmaf(sf[nb][r], SC, -4.0f));
          sf[nb][r] = p;
          lsum[r] += p;
        }
#pragma unroll
      for (int nb = 0; nb < 4; ++nb) {
        uint2v dw;
        asm("v_cvt_pk_bf16_f32 %0, %1, %2"
            : "=v"(dw.x) : "v"(sf[nb][0]), "v"(sf[nb][1]));
        asm("v_cvt_pk_bf16_f32 %0, %1, %2"
            : "=v"(dw.y) : "v"(sf[nb][2]), "v"(sf[nb][3]));
        *(uint2v*)(Pt + (nb * 16 + l15) * 40 + (g << 3)) = dw;
      }
      asm volatile("s_waitcnt lgkmcnt(0)" ::: "memory");  // same-wave P RAW
#pragma unroll
      for (int ks = 0; ks < 2; ++ks) {
        const char* pp = Pt + (ks * 32 + g * 8) * 40 + (l15 << 1);
        bf16x8 pa;
#pragma unroll
        for (int jj = 0; jj < 8; ++jj)
          pa[jj] = *(const short*)(pp + jj * 40);
        __builtin_amdgcn_s_setprio(1);
#pragma unroll
        for (int nb = 0; nb < 4; ++nb) {
          const int drow = nb * 16 + l15;
          bf16x8 vb = *(const bf16x8*)(Vs + drow * 128 +
                                       (((ks * 32 + g * 8) << 1) ^ ((drow & 7) << 4)));
          acc[nb] = MFMA_BF16(pa, vb, acc[nb]);
        }
        __builtin_amdgcn_s_setprio(0);
      }
      VMCNT(0);  // drains only the 2 body-top stage ops (issued one compute-body ago)
      BAR();
    }
    // one 16-lane sum reduce per q-row
#pragma unroll
    for (int r = 0; r < 4; ++r) {
      float s = lsum[r];
      s += __shfl_xor(s, 1);
      s += __shfl_xor(s, 2);
      s += __shfl_xor(s, 4);
      s += __shfl_xor(s, 8);
      lsum[r] = s;
    }
    float inv[4];
#pragma unroll
    for (int r = 0; r < 4; ++r) inv[r] = 1.0f / lsum[r];
#pragma unroll
    for (int nb = 0; nb < 4; ++nb)
#pragma unroll
      for (int r = 0; r < 4; ++r)
        ctx[(size_t)(b * 2048 + q0w + 4 * g + r) * 1024 + h * 64 + nb * 16 + l15] =
            bf16rn(acc[nb][r] * inv[r]);
  }
}

extern "C" void kernel_launch(void* const* d_in, const int* in_sizes, int n_in,
                              void* d_out, int out_size, void* d_ws, size_t ws_size,
                              hipStream_t stream)
{
  const float* x   = (const float*)d_in[0];
  const float* l1s = (const float*)d_in[1];
  const float* l1b = (const float*)d_in[2];
  const float* l2s = (const float*)d_in[3];
  const float* l2b = (const float*)d_in[4];
  const float* Wq  = (const float*)d_in[5];
  const float* Wk  = (const float*)d_in[6];
  const float* Wv  = (const float*)d_in[7];
  const float* Wo  = (const float*)d_in[8];
  const float* bo  = (const float*)d_in[9];
  const float* Wfc = (const float*)d_in[10];
  const float* bfc = (const float*)d_in[11];
  const float* Wpj = (const float*)d_in[12];
  const float* bpj = (const float*)d_in[13];
  float* out = (float*)d_out;
  char* ws = (char*)d_ws;

  unsigned short* wT   = (unsigned short*)ws;                // 24MB weights
  unsigned short* wqkT = wT;                                 // [2048][1024] fused Q|K
  unsigned short* wvT  = wT + 2097152u;
  unsigned short* woT  = wT + 3145728u;
  unsigned short* wfcT = wT + 4194304u;
  unsigned short* wpjT = wT + 8388608u;
  unsigned short* ln1x = (unsigned short*)(ws + 25165824u);  // 16MB
  unsigned short* qkb  = (unsigned short*)(ws + 41943040u);  // 32MB [8192][2048]
  unsigned short* vTb  = (unsigned short*)(ws + 75497472u);  // 16MB
  unsigned short* ctx  = (unsigned short*)(ws + 92274688u);  // 16MB (reused as ln2x)
  unsigned short* ln2x = ctx;
  float* hbuf          = (float*)(ws + 109051904u);          // 32MB
  unsigned short* fcb  = (unsigned short*)(ws + 25165824u);  // 64MB, reuses ln1x..vTb

  convT_kernel<<<3072, 256, 0, stream>>>(Wq, Wk, Wv, Wo, Wfc, Wpj, wT);
  ln_kernel<<<8192, 256, 0, stream>>>(x, l1s, l1b, ln1x);
  g128<0><<<1024, 256, 49152, stream>>>(ln1x, wqkT, 2048, 1024,
                                        qkb, nullptr, nullptr, nullptr);
  g128<1><<<512, 256, 49152, stream>>>(ln1x, wvT, 1024, 1024,
                                       vTb, nullptr, nullptr, nullptr);
  attn_kernel<<<dim3(64, 8), 512, 0, stream>>>(qkb, qkb + 1024, vTb, ctx);
  g128<2><<<512, 256, 49152, stream>>>(ctx, woT, 1024, 1024,
                                       nullptr, hbuf, bo, x);
  ln_kernel<<<8192, 256, 0, stream>>>(hbuf, l2s, l2b, ln2x);
  g128<3><<<2048, 256, 49152, stream>>>(ln2x, wfcT, 4096, 1024,
                                        fcb, nullptr, bfc, nullptr);
  g128<2><<<512, 256, 49152, stream>>>(fcb, wpjT, 1024, 4096,
                                       nullptr, out, bpj, hbuf);
}